// Round 1
// baseline (3016.316 us; speedup 1.0000x reference)
//
#include <hip/hip_runtime.h>
#include <hip/hip_bf16.h>

typedef __hip_bfloat16 bf16;
typedef __attribute__((ext_vector_type(8))) short short8;
typedef __attribute__((ext_vector_type(4))) float f32x4;

#define GLB_AS(p) ((const __attribute__((address_space(1))) void*)(p))
#define LDS_AS(p) ((__attribute__((address_space(3))) void*)(p))

// ---------------------------------------------------------------------------
// 8-phase 256x256 bf16 GEMM (plain-HIP port of the HK cdna4 schedule).
// C[m,n] = sum_k A[m,k]*B[n,k] + bias[n]; EPI 1 = bf16 out, EPI 2 = +GELU.
// 8 waves (2Mx4N), BK=64, LDS = 2dbuf x {A,B} x 2 K-halves x 256x32 = 128KB.
// Staging stream runs 7 half-tiles ahead -> single s_waitcnt vmcnt(6) per
// K-tile (drain 0 only at the final boundary). Half-tile stream order
// [B-k0, A-k0, B-k1, A-k1] gives every LDS overwrite >=1 barrier of margin
// after its last reader. LDS reads are ds_read_b128 with slot-XOR swizzle
// (slot ^= (row>>1)&3): 2 lanes per 16B bank-group per quarter-wave = b128
// floor, zero extra bank conflicts. Swizzle applied on BOTH sides: linear
// global_load_lds dest + pre-swizzled per-lane global source (involution).
// ---------------------------------------------------------------------------
template<int EPI>
__global__ __launch_bounds__(512, 2) void gemm8p(
    const bf16* __restrict__ A, const bf16* __restrict__ Bm, bf16* __restrict__ C,
    int K, int lda, int ldb, int ldc, const float* __restrict__ bias)
{
    __shared__ __align__(16) bf16 Als[2][2][8192];   // [dbuf][khalf][256*32]
    __shared__ __align__(16) bf16 Bls[2][2][8192];

    const int tid  = threadIdx.x;
    const int wave = tid >> 6;
    const int lane = tid & 63;
    const int wr = wave >> 2;        // 0..1 : 128-row slice
    const int wc = wave & 3;         // 0..3 : 64-col slice

    // XCD-chunked bijective swizzle (all grids here have nwg % 8 == 0),
    // then GROUP_M=8 supertile for L2 A-panel reuse.
    const int Mt = gridDim.x, Nt = gridDim.y;
    int pid = blockIdx.y * Mt + blockIdx.x;
    const int cpx = (Mt * Nt) >> 3;
    pid = (pid & 7) * cpx + (pid >> 3);
    int m_t, n_t;
    {
        const int grpsz = 8 * Nt;
        const int grp = pid / grpsz;
        const int first = grp * 8;
        int rem = Mt - first; if (rem > 8) rem = 8;
        const int loc = pid - grp * grpsz;
        m_t = first + loc % rem;
        n_t = loc / rem;
    }
    const int m0 = m_t << 8;
    const int n0 = n_t << 8;
    const int nt = K >> 6;           // K-tiles (>= 2 for all call sites)

    // ---- staging (global -> LDS, linear dest, pre-swizzled source) ----
    // thread -> (row = tid>>2, linear slot = tid&3); source slot XOR (row>>1)&3
    const int s_r  = tid >> 2;                              // 0..127
    const int s_sl = ((tid & 3) ^ ((tid >> 3) & 3)) << 3;   // element offset
    const bf16* As0 = A  + (long)(m0 + s_r) * lda + s_sl;
    const bf16* Bs0 = Bm + (long)(n0 + s_r) * ldb + s_sl;
    const long ldal = (long)lda << 7;                       // +128 rows
    const long ldbl = (long)ldb << 7;
    char* AB = (char*)Als;
    char* BB = (char*)Bls;
    const int wofs = wave << 10;                            // wave's 1KB slab

#define STAGE_A(d, kh, tt) do { \
    const bf16* g_ = As0 + ((long)(tt) << 6) + ((kh) << 5); \
    char* dst_ = AB + ((((d) << 1) + (kh)) << 14) + wofs; \
    __builtin_amdgcn_global_load_lds(GLB_AS(g_), LDS_AS(dst_), 16, 0, 0); \
    __builtin_amdgcn_global_load_lds(GLB_AS(g_ + ldal), LDS_AS(dst_ + 8192), 16, 0, 0); \
  } while (0)
#define STAGE_B(d, kh, tt) do { \
    const bf16* g_ = Bs0 + ((long)(tt) << 6) + ((kh) << 5); \
    char* dst_ = BB + ((((d) << 1) + (kh)) << 14) + wofs; \
    __builtin_amdgcn_global_load_lds(GLB_AS(g_), LDS_AS(dst_), 16, 0, 0); \
    __builtin_amdgcn_global_load_lds(GLB_AS(g_ + ldbl), LDS_AS(dst_ + 8192), 16, 0, 0); \
  } while (0)
#define BAR() do { asm volatile("" ::: "memory"); \
    __builtin_amdgcn_s_barrier(); asm volatile("" ::: "memory"); } while (0)

    // prologue: stream positions 0..6 (tile0 complete + 3 halves of tile1)
    STAGE_B(0, 0, 0); STAGE_A(0, 0, 0); STAGE_B(0, 1, 0); STAGE_A(0, 1, 0);
    STAGE_B(1, 0, 1); STAGE_A(1, 0, 1); STAGE_B(1, 1, 1);

    f32x4 acc[8][4];
#pragma unroll
    for (int i = 0; i < 8; ++i)
#pragma unroll
        for (int j = 0; j < 4; ++j) acc[i][j] = (f32x4){0.f, 0.f, 0.f, 0.f};

    // ---- ds_read fragment addressing (swizzled) ----
    const int fr  = lane & 15;                                   // frag row
    const int swz = (((lane >> 4) ^ ((lane >> 1) & 3)) << 4);    // 16B slot
    const int aoff = (wr << 13) + fr * 64 + swz;                 // wr*128*64
    const int boff = (wc << 12) + fr * 64 + swz;                 // wc*64*64

    asm volatile("s_waitcnt vmcnt(6)" ::: "memory");  // tile 0 fully landed
    __builtin_amdgcn_s_barrier();
    asm volatile("" ::: "memory");

    int d = 0;
    for (int t = 0; t < nt; ++t, d ^= 1) {
        short8 b[4];
#pragma unroll
        for (int p = 0; p < 4; ++p) {
            const int kh = p >> 1, rh = p & 1;
            const char* Ahb = AB + (((d << 1) + kh) << 14);
            const char* Bhb = BB + (((d << 1) + kh) << 14);
            short8 a[4];
#pragma unroll
            for (int i = 0; i < 4; ++i)
                a[i] = *(const short8*)(Ahb + aoff + rh * 4096 + i * 1024);
            if ((p & 1) == 0) {
#pragma unroll
                for (int j = 0; j < 4; ++j)
                    b[j] = *(const short8*)(Bhb + boff + j * 1024);
            }
            // stage one half-tile (stream position 4t+7+p); region's last
            // reader finished >=1 barrier ago by construction.
            if (p == 0)      { if (t + 1 < nt) STAGE_A(d ^ 1, 1, t + 1); }
            else if (p == 1) { if (t + 2 < nt) STAGE_B(d, 0, t + 2); }
            else if (p == 2) { if (t + 2 < nt) STAGE_A(d, 0, t + 2); }
            else             { if (t + 2 < nt) STAGE_B(d, 1, t + 2); }
            BAR();
            asm volatile("s_waitcnt lgkmcnt(0)" ::: "memory");
            __builtin_amdgcn_sched_barrier(0);
            __builtin_amdgcn_s_setprio(1);
#pragma unroll
            for (int i = 0; i < 4; ++i)
#pragma unroll
                for (int j = 0; j < 4; ++j)
                    acc[rh * 4 + i][j] = __builtin_amdgcn_mfma_f32_16x16x32_bf16(
                        a[i], b[j], acc[rh * 4 + i][j], 0, 0, 0);
            __builtin_amdgcn_s_setprio(0);
            if (p == 3 && t < nt - 1) {
                if (t == nt - 2) asm volatile("s_waitcnt vmcnt(0)" ::: "memory");
                else             asm volatile("s_waitcnt vmcnt(6)" ::: "memory");
            }
            BAR();
        }
    }
#undef STAGE_A
#undef STAGE_B
#undef BAR

    // epilogue: C/D layout col=lane&15, row=(lane>>4)*4+reg
    const int ccol = lane & 15;
    const int crow = (lane >> 4) << 2;
    const int colb  = n0 + (wc << 6) + ccol;
    const int rowbb = m0 + (wr << 7) + crow;
#pragma unroll
    for (int j = 0; j < 4; ++j) {
        const int col = colb + (j << 4);
        const float bv = bias[col];
#pragma unroll
        for (int i = 0; i < 8; ++i) {
            const int rowb = rowbb + (i << 4);
#pragma unroll
            for (int r2 = 0; r2 < 4; ++r2) {
                float v = acc[i][j][r2] + bv;
                if (EPI == 2) v = 0.5f * v * (1.0f + erff(v * 0.70710678118f));
                C[(long)(rowb + r2) * ldc + col] = __float2bfloat16(v);
            }
        }
    }
}

// ---------------------------------------------------------------------------
// Legacy 128x128 GEMM: kept for the small attention GEMMs (EPI 3 = scores,
// EPI 4 = causal PV) where the 256^2 schedule doesn't fit the shapes.
// ---------------------------------------------------------------------------
template<int EPI>
__global__ __launch_bounds__(256) void gemm_bf16(
    const bf16* __restrict__ Ain, const bf16* __restrict__ Bin, void* __restrict__ Cv,
    int K, int lda, int ldb, int ldc,
    long sAo, long sAi, long sBo, long sBi, long sCo, long sCi, int nInner,
    const float* __restrict__ bias, const float* __restrict__ demb,
    float scale)
{
    __shared__ __align__(16) bf16 Als[128 * 64];
    __shared__ __align__(16) bf16 Bls[128 * 64];

    const int z  = blockIdx.z;
    const int zo = z / nInner;
    const int zi = z - zo * nInner;
    const bf16* A = Ain + zo * sAo + zi * sAi;
    const bf16* B = Bin + zo * sBo + zi * sBi;
    const long coff = zo * sCo + zi * sCi;

    int m_t, n_t;
    if (EPI == 3) {
        m_t = (blockIdx.x + 1) >> 1;   // 0,1,1
        n_t = blockIdx.x >> 1;         // 0,0,1
    } else {
        const int Mt = gridDim.x, Nt = gridDim.y;
        if (Mt >= 8) {
            const int pid = blockIdx.y * Mt + blockIdx.x;
            const int grpsz = 8 * Nt;
            const int grp = pid / grpsz;
            const int first = grp * 8;
            int rem = Mt - first; if (rem > 8) rem = 8;
            const int loc = pid - grp * grpsz;
            m_t = first + loc % rem;
            n_t = loc / rem;
        } else { m_t = blockIdx.x; n_t = blockIdx.y; }
    }
    const int m0 = m_t * 128;
    const int n0 = n_t * 128;

    const int Keff = (EPI == 4) ? (m_t + 1) * 128 : K;

    const int tid  = threadIdx.x;
    const int wave = tid >> 6;
    const int lane = tid & 63;
    const int wm = (wave >> 1) * 64;
    const int wn = (wave & 1) * 64;

    f32x4 acc[4][4];
#pragma unroll
    for (int i = 0; i < 4; ++i)
#pragma unroll
        for (int j = 0; j < 4; ++j) acc[i][j] = (f32x4){0.f, 0.f, 0.f, 0.f};

    const int srow = lane >> 3;
    const int scol = (((lane & 7) ^ srow) << 3);

    for (int k0 = 0; k0 < Keff; k0 += 64) {
        __syncthreads();
#pragma unroll
        for (int c = 0; c < 4; ++c) {
            const int chunk = (wave << 2) + c;
            const int row = (chunk << 3) + srow;
            const bf16* ga = A + (long)(m0 + row) * lda + k0 + scol;
            const bf16* gb = B + (long)(n0 + row) * ldb + k0 + scol;
            __builtin_amdgcn_global_load_lds(GLB_AS(ga), LDS_AS(&Als[chunk << 9]), 16, 0, 0);
            __builtin_amdgcn_global_load_lds(GLB_AS(gb), LDS_AS(&Bls[chunk << 9]), 16, 0, 0);
        }
        __syncthreads();

#pragma unroll
        for (int kk = 0; kk < 2; ++kk) {
            const int CB = (kk << 2) + (lane >> 4);
            const int r = lane & 15;
            short8 afr[4], bfr[4];
#pragma unroll
            for (int i = 0; i < 4; ++i) {
                const int ar = wm + (i << 4) + r;
                afr[i] = *(const short8*)&Als[ar * 64 + ((CB ^ (ar & 7)) << 3)];
            }
#pragma unroll
            for (int j = 0; j < 4; ++j) {
                const int br = wn + (j << 4) + r;
                bfr[j] = *(const short8*)&Bls[br * 64 + ((CB ^ (br & 7)) << 3)];
            }
#pragma unroll
            for (int i = 0; i < 4; ++i)
#pragma unroll
                for (int j = 0; j < 4; ++j)
                    acc[i][j] = __builtin_amdgcn_mfma_f32_16x16x32_bf16(
                        afr[i], bfr[j], acc[i][j], 0, 0, 0);
        }
    }

    const int ccol = lane & 15;
    const int crow = (lane >> 4) << 2;
#pragma unroll
    for (int i = 0; i < 4; ++i) {
#pragma unroll
        for (int j = 0; j < 4; ++j) {
            const int col  = n0 + wn + (j << 4) + ccol;
            const int rowb = m0 + wm + (i << 4) + crow;
#pragma unroll
            for (int r2 = 0; r2 < 4; ++r2) {
                const int row = rowb + r2;
                float v = acc[i][j][r2];
                const long cidx = coff + (long)row * ldc + col;
                if (EPI == 3) {
                    int d0 = row - col;
                    int ad = d0 < 0 ? -d0 : d0;
                    if (ad > 250) ad = 250;
                    ((bf16*)Cv)[cidx] = __float2bfloat16(v * scale + demb[ad * 8 + zi]);
                } else if (EPI == 0) {
                    if (bias) v += bias[col];
                    ((float*)Cv)[cidx] = v;
                } else if (EPI == 1 || EPI == 4) {
                    if (bias) v += bias[col];
                    ((bf16*)Cv)[cidx] = __float2bfloat16(v);
                } else {
                    v += bias[col];
                    v = 0.5f * v * (1.0f + erff(v * 0.70710678118f));
                    ((bf16*)Cv)[cidx] = __float2bfloat16(v);
                }
            }
        }
    }
}

// ---------------------------------------------------------------------------
// merged fp32 -> bf16 cast over 4 weight arrays (counts in 4-elem groups)
// ---------------------------------------------------------------------------
__global__ void cast4_kernel(const float* __restrict__ s0, const float* __restrict__ s1,
                             const float* __restrict__ s2, const float* __restrict__ s3,
                             bf16* __restrict__ d0, bf16* __restrict__ d1,
                             bf16* __restrict__ d2, bf16* __restrict__ d3,
                             long n0, long n1, long n2, long n3)
{
    long i = (long)blockIdx.x * blockDim.x + threadIdx.x;
    const float* s; bf16* d; long base;
    if (i < n0)                { s = s0; d = d0; base = 0; }
    else if (i < n0 + n1)      { s = s1; d = d1; base = n0; }
    else if (i < n0 + n1 + n2) { s = s2; d = d2; base = n0 + n1; }
    else if (i < n0+n1+n2+n3)  { s = s3; d = d3; base = n0 + n1 + n2; }
    else return;
    const long j = i - base;
    f32x4 v = *(const f32x4*)(s + j * 4);
    bf16 t[4] = {__float2bfloat16(v[0]), __float2bfloat16(v[1]),
                 __float2bfloat16(v[2]), __float2bfloat16(v[3])};
    *(short4*)(d + j * 4) = *(const short4*)t;
}

// ---------------------------------------------------------------------------
// embedding: x[t,:] = token_emb[seq[t]] * 32  (sqrt(1024)); writes f32 + bf16
// ---------------------------------------------------------------------------
__global__ void embed_kernel(const int* __restrict__ seq, const float* __restrict__ emb,
                             float* __restrict__ x, bf16* __restrict__ xb)
{
    const long t = blockIdx.x;
    const int tok = seq[t];
    const int tid = threadIdx.x;
    f32x4 v = *(const f32x4*)(emb + (long)tok * 1024 + tid * 4);
    v *= 32.0f;
    *(f32x4*)(x + t * 1024 + tid * 4) = v;
    bf16 tq[4] = {__float2bfloat16(v[0]), __float2bfloat16(v[1]),
                  __float2bfloat16(v[2]), __float2bfloat16(v[3])};
    *(short4*)(xb + t * 1024 + tid * 4) = *(const short4*)tq;
}

// ---------------------------------------------------------------------------
// Causal softmax over rows of 256 (scores bf16 -> probs bf16). 1 wave/row.
// ---------------------------------------------------------------------------
__global__ void softmax_kernel(const bf16* __restrict__ scores, bf16* __restrict__ probs)
{
    const long row = (long)blockIdx.x * 4 + (threadIdx.x >> 6);
    const int q = (int)(row & 255);
    const int lane = threadIdx.x & 63;
    const int kbase = lane * 4;
    short4 sv = *(const short4*)(scores + row * 256 + kbase);
    const bf16* sp = (const bf16*)&sv;
    float v0 = (kbase + 0 <= q) ? __bfloat162float(sp[0]) : -1e30f;
    float v1 = (kbase + 1 <= q) ? __bfloat162float(sp[1]) : -1e30f;
    float v2 = (kbase + 2 <= q) ? __bfloat162float(sp[2]) : -1e30f;
    float v3 = (kbase + 3 <= q) ? __bfloat162float(sp[3]) : -1e30f;
    float m = fmaxf(fmaxf(v0, v1), fmaxf(v2, v3));
#pragma unroll
    for (int off = 32; off; off >>= 1) m = fmaxf(m, __shfl_xor(m, off));
    float e0 = (kbase + 0 <= q) ? __expf(v0 - m) : 0.f;
    float e1 = (kbase + 1 <= q) ? __expf(v1 - m) : 0.f;
    float e2 = (kbase + 2 <= q) ? __expf(v2 - m) : 0.f;
    float e3 = (kbase + 3 <= q) ? __expf(v3 - m) : 0.f;
    float s = e0 + e1 + e2 + e3;
#pragma unroll
    for (int off = 32; off; off >>= 1) s += __shfl_xor(s, off);
    const float inv = 1.0f / s;
    bf16 tq[4] = {__float2bfloat16(e0 * inv), __float2bfloat16(e1 * inv),
                  __float2bfloat16(e2 * inv), __float2bfloat16(e3 * inv)};
    *(short4*)(probs + row * 256 + kbase) = *(const short4*)tq;
}

// ---------------------------------------------------------------------------
// V transpose: qkv[b,s,2E + h*128 + d] -> vt[b,h,d,s]  (bf16), LDS 32x33 tile
// ---------------------------------------------------------------------------
__global__ void transpose_v(const bf16* __restrict__ qkv, bf16* __restrict__ vt)
{
    __shared__ bf16 tile[32][33];
    const int bh = blockIdx.y;
    const int st = blockIdx.x & 7;
    const int dt = blockIdx.x >> 3;
    const int tx = threadIdx.x & 31;
    const int ty = threadIdx.x >> 5;
    const int b = bh >> 3, h = bh & 7;
    const bf16* src = qkv + ((long)b * 256) * 3072 + 2048 + h * 128 + dt * 32;
#pragma unroll
    for (int i = 0; i < 4; ++i) {
        const int s = st * 32 + ty * 4 + i;
        tile[ty * 4 + i][tx] = src[(long)s * 3072 + tx];
    }
    __syncthreads();
    bf16* dst = vt + ((long)bh * 128 + dt * 32) * 256 + st * 32;
#pragma unroll
    for (int i = 0; i < 4; ++i) {
        const int dl = ty * 4 + i;
        dst[(long)dl * 256 + tx] = tile[tx][dl];
    }
}

// ---------------------------------------------------------------------------
// LayerNorm over E=1024: out = (x [+ res(bf16)] - mean)/sqrt(var+1e-5)*g + b
// ---------------------------------------------------------------------------
__global__ void ln_kernel(const float* __restrict__ x, const bf16* __restrict__ res,
                          const float* __restrict__ g, const float* __restrict__ bta,
                          float* __restrict__ outf, bf16* __restrict__ outb,
                          int has_res, int has_bf)
{
    const long t = blockIdx.x;
    const int tid = threadIdx.x;
    f32x4 v = *(const f32x4*)(x + t * 1024 + tid * 4);
    if (has_res) {
        short4 rv = *(const short4*)(res + t * 1024 + tid * 4);
        const bf16* rp = (const bf16*)&rv;
#pragma unroll
        for (int q = 0; q < 4; ++q) v[q] += __bfloat162float(rp[q]);
    }
    float s  = v[0] + v[1] + v[2] + v[3];
    float ss = v[0]*v[0] + v[1]*v[1] + v[2]*v[2] + v[3]*v[3];
#pragma unroll
    for (int off = 32; off; off >>= 1) {
        s  += __shfl_xor(s, off);
        ss += __shfl_xor(ss, off);
    }
    __shared__ float red[8];
    const int w = tid >> 6;
    if ((tid & 63) == 0) { red[w] = s; red[4 + w] = ss; }
    __syncthreads();
    s  = red[0] + red[1] + red[2] + red[3];
    ss = red[4] + red[5] + red[6] + red[7];
    const float mean = s * (1.0f / 1024.0f);
    const float var  = ss * (1.0f / 1024.0f) - mean * mean;
    const float rstd = rsqrtf(var + 1e-5f);
    f32x4 gv = *(const f32x4*)(g + tid * 4);
    f32x4 bv = *(const f32x4*)(bta + tid * 4);
    f32x4 o;
#pragma unroll
    for (int q = 0; q < 4; ++q) o[q] = (v[q] - mean) * rstd * gv[q] + bv[q];
    *(f32x4*)(outf + t * 1024 + tid * 4) = o;
    if (has_bf) {
        bf16 tq[4] = {__float2bfloat16(o[0]), __float2bfloat16(o[1]),
                      __float2bfloat16(o[2]), __float2bfloat16(o[3])};
        *(short4*)(outb + t * 1024 + tid * 4) = *(const short4*)tq;
    }
}

// ---------------------------------------------------------------------------
// logits: out[t,n] = xf[t,:].dot(W[n,:]) + b[n], N=45, K=1024 (fp32)
// ---------------------------------------------------------------------------
__global__ void gen_kernel(const float* __restrict__ xf, const float* __restrict__ W,
                           const float* __restrict__ bias, float* __restrict__ out)
{
    const long t = (long)blockIdx.x * 4 + (threadIdx.x >> 6);
    const int lane = threadIdx.x & 63;
    const float* xr = xf + t * 1024;
    float xv[16];
#pragma unroll
    for (int j = 0; j < 16; ++j) xv[j] = xr[lane + 64 * j];
    for (int n = 0; n < 45; ++n) {
        const float* wr = W + (long)n * 1024;
        float a = 0.f;
#pragma unroll
        for (int j = 0; j < 16; ++j) a += xv[j] * wr[lane + 64 * j];
#pragma unroll
        for (int off = 32; off; off >>= 1) a += __shfl_xor(a, off);
        if (lane == 0) out[t * 45 + n] = a + bias[n];
    }
}

// ---------------------------------------------------------------------------
extern "C" void kernel_launch(void* const* d_in, const int* in_sizes, int n_in,
                              void* d_out, int out_size, void* d_ws, size_t ws_size,
                              hipStream_t stream)
{
    (void)in_sizes; (void)n_in; (void)out_size; (void)ws_size;
    const int*   seq  = (const int*)d_in[0];
    const float* temb = (const float*)d_in[1];
    const float* demb = (const float*)d_in[2];
    const float* Wqkv = (const float*)d_in[3];
    const float* bqkv = (const float*)d_in[4];
    const float* Wo   = (const float*)d_in[5];
    const float* bo   = (const float*)d_in[6];
    const float* W1   = (const float*)d_in[7];
    const float* b1   = (const float*)d_in[8];
    const float* W2   = (const float*)d_in[9];
    const float* b2   = (const float*)d_in[10];
    const float* ln1g = (const float*)d_in[11];
    const float* ln1b = (const float*)d_in[12];
    const float* ln2g = (const float*)d_in[13];
    const float* ln2b = (const float*)d_in[14];
    const float* fng  = (const float*)d_in[15];
    const float* fnb  = (const float*)d_in[16];
    const float* genW = (const float*)d_in[17];
    const float* genb = (const float*)d_in[18];
    float* out = (float*)d_out;

    char* ws = (char*)d_ws;
    size_t off = 0;
    auto alloc = [&](size_t bytes) -> char* {
        char* p = ws + off;
        off += (bytes + 255) & ~(size_t)255;
        return p;
    };

    bf16*  wqkv_l = (bf16*)alloc(3072ULL * 1024 * 2);
    bf16*  wo_l   = (bf16*)alloc(1024ULL * 1024 * 2);
    bf16*  w1_l   = (bf16*)alloc(4096ULL * 1024 * 2);
    bf16*  w2_l   = (bf16*)alloc(1024ULL * 4096 * 2);
    float* x      = (float*)alloc(8192ULL * 1024 * 4);
    bf16*  xb     = (bf16*)alloc(8192ULL * 1024 * 2);
    char*  qkvreg = alloc(8192ULL * 3072 * 2);
    char*  R      = alloc(8192ULL * 4096 * 2);
    bf16*  tmpb   = (bf16*)alloc(8192ULL * 1024 * 2);

    bf16*  qkvb   = (bf16*)qkvreg;
    bf16*  attnb  = (bf16*)qkvreg;
    float* lnout  = (float*)qkvreg;
    bf16*  scoreb = (bf16*)R;
    bf16*  probs  = (bf16*)(R + 8192ULL * 4096);
    bf16*  vt     = (bf16*)R;
    bf16*  hbuf   = (bf16*)R;

    const dim3 blk(256);
    const dim3 blk8(512);

    embed_kernel<<<8192, blk, 0, stream>>>(seq, temb, x, xb);

    for (int l = 0; l < 6; ++l) {
        cast4_kernel<<<12288, blk, 0, stream>>>(
            Wqkv + (long)l * 3072 * 1024, Wo + (long)l * 1024 * 1024,
            W1 + (long)l * 4096 * 1024,   W2 + (long)l * 4096 * 1024,
            wqkv_l, wo_l, w1_l, w2_l,
            786432, 262144, 1048576, 1048576);

        // QKV: [8192,1024] x [3072,1024]^T -> bf16 [8192,3072]
        gemm8p<1><<<dim3(32, 12), blk8, 0, stream>>>(xb, wqkv_l, qkvb,
            1024, 1024, 1024, 3072, bqkv + (long)l * 3072);

        // scores[b,h,q,k] = scale*(Q.K) + dist bias (bf16); 3 causal tiles
        gemm_bf16<3><<<dim3(3, 1, 256), blk, 0, stream>>>(qkvb, qkvb + 1024, scoreb,
            128, 3072, 3072, 256,
            786432, 128, 786432, 128, 524288, 65536, 8,
            nullptr, demb, 0.08838834764831845f);

        softmax_kernel<<<16384, blk, 0, stream>>>(scoreb, probs);
        transpose_v<<<dim3(32, 256), blk, 0, stream>>>(qkvb, vt);

        // O[b,q,h*128+d] = P.V ; causal K-limit per q-tile
        gemm_bf16<4><<<dim3(2, 1, 256), blk, 0, stream>>>(probs, vt, attnb,
            256, 256, 256, 1024,
            524288, 65536, 262144, 32768, 262144, 128, 8,
            nullptr, nullptr, 0.f);

        // Wo: [8192,1024] x [1024,1024]^T -> bf16 tmpb
        gemm8p<1><<<dim3(32, 4), blk8, 0, stream>>>(attnb, wo_l, tmpb,
            1024, 1024, 1024, 1024, bo + (long)l * 1024);

        ln_kernel<<<8192, blk, 0, stream>>>(x, tmpb, ln1g + (long)l * 1024,
                                            ln1b + (long)l * 1024, x, xb, 1, 1);

        // FFN1 + GELU: [8192,1024] x [4096,1024]^T -> bf16 [8192,4096]
        gemm8p<2><<<dim3(32, 16), blk8, 0, stream>>>(xb, w1_l, hbuf,
            1024, 1024, 1024, 4096, b1 + (long)l * 4096);

        // FFN2: [8192,4096] x [1024,4096]^T -> bf16 tmpb
        gemm8p<1><<<dim3(32, 4), blk8, 0, stream>>>(hbuf, w2_l, tmpb,
            4096, 4096, 4096, 1024, b2 + (long)l * 1024);

        ln_kernel<<<8192, blk, 0, stream>>>(x, tmpb, ln2g + (long)l * 1024,
                                            ln2b + (long)l * 1024, x, xb, 1, 1);
    }

    ln_kernel<<<8192, blk, 0, stream>>>(x, nullptr, fng, fnb, lnout, nullptr, 0, 0);
    gen_kernel<<<2048, blk, 0, stream>>>(lnout, genW, genb, out);
}

// Round 2
// 2477.910 us; speedup vs baseline: 1.2173x; 1.2173x over previous
//
#include <hip/hip_runtime.h>
#include <hip/hip_bf16.h>

typedef __hip_bfloat16 bf16;
typedef __attribute__((ext_vector_type(8))) short short8;
typedef __attribute__((ext_vector_type(4))) float f32x4;

#define GLB_AS(p) ((const __attribute__((address_space(1))) void*)(p))
#define LDS_AS(p) ((__attribute__((address_space(3))) void*)(p))

// ---------------------------------------------------------------------------
// Generic batched bf16 MFMA GEMM: C[m,n] = sum_k A[m,k]*B[n,k]  (+ epilogue)
// Tile: BM=BN=128, BK=64. Block=256 threads (4 waves, 2x2 of 64x64).
// LDS XOR-swizzled (slot s of row r holds col-block s^r) -> 0 bank conflicts.
// This revision: all 16 LDS fragment byte-offsets and all 8 global staging
// pointers are hoisted out of the K-loop (they are loop-invariant / affine);
// __launch_bounds__(256,3) gives the register allocator room (~170 VGPR) to
// keep them live instead of rematerializing ~120 VALU ops per K-step, which
// the round-0 counters showed was the issue bottleneck (VALUBusy 65%,
// MfmaUtil 27%, 80 VGPR).
// EPI: 0 = +bias -> f32; 1 = +bias -> bf16; 2 = +bias,GELU -> bf16;
//      3 = *scale + dist bias -> bf16 scores (causal tile remap);
//      4 = bf16 out, causal PV (K_eff = (m_t+1)*128)
// ---------------------------------------------------------------------------
template<int EPI>
__global__ __launch_bounds__(256, 3) void gemm_bf16(
    const bf16* __restrict__ Ain, const bf16* __restrict__ Bin, void* __restrict__ Cv,
    int K, int lda, int ldb, int ldc,
    long sAo, long sAi, long sBo, long sBi, long sCo, long sCi, int nInner,
    const float* __restrict__ bias, const float* __restrict__ demb,
    float scale)
{
    __shared__ __align__(16) bf16 Als[128 * 64];
    __shared__ __align__(16) bf16 Bls[128 * 64];

    const int z  = blockIdx.z;
    const int zo = z / nInner;
    const int zi = z - zo * nInner;
    const bf16* A = Ain + zo * sAo + zi * sAi;
    const bf16* B = Bin + zo * sBo + zi * sBi;
    const long coff = zo * sCo + zi * sCi;

    int m_t, n_t;
    if (EPI == 3) {
        // causal tile remap: only lower-triangular 128-tiles
        m_t = (blockIdx.x + 1) >> 1;   // 0,1,1
        n_t = blockIdx.x >> 1;         // 0,0,1
    } else {
        // GROUP_M=8 supertile swizzle for L2 locality
        const int Mt = gridDim.x, Nt = gridDim.y;
        if (Mt >= 8) {
            const int pid = blockIdx.y * Mt + blockIdx.x;
            const int grpsz = 8 * Nt;
            const int grp = pid / grpsz;
            const int first = grp * 8;
            int rem = Mt - first; if (rem > 8) rem = 8;
            const int loc = pid - grp * grpsz;
            m_t = first + loc % rem;
            n_t = loc / rem;
        } else { m_t = blockIdx.x; n_t = blockIdx.y; }
    }
    const int m0 = m_t * 128;
    const int n0 = n_t * 128;

    const int Keff = (EPI == 4) ? (m_t + 1) * 128 : K;

    const int tid  = threadIdx.x;
    const int wave = tid >> 6;
    const int lane = tid & 63;
    const int wm = (wave >> 1) * 64;   // wave row offset in 128-tile
    const int wn = (wave & 1) * 64;    // wave col offset

    f32x4 acc[4][4];
#pragma unroll
    for (int i = 0; i < 4; ++i)
#pragma unroll
        for (int j = 0; j < 4; ++j) acc[i][j] = (f32x4){0.f, 0.f, 0.f, 0.f};

    // ---- hoisted staging addresses ----
    // chunk = 8 rows x 64 cols; lane i -> row i>>3, col-block (i&7)^(i>>3)
    const int srow = lane >> 3;                        // 0..7
    const int scol = (((lane & 7) ^ srow) << 3);       // XOR-swizzled col
    const bf16* gaP[4];
    const bf16* gbP[4];
    bf16* ldsA[4];
    bf16* ldsB[4];
#pragma unroll
    for (int c = 0; c < 4; ++c) {
        const int chunk = (wave << 2) + c;
        const int row = (chunk << 3) + srow;
        gaP[c] = A + (long)(m0 + row) * lda + scol;
        gbP[c] = B + (long)(n0 + row) * ldb + scol;
        ldsA[c] = &Als[chunk << 9];
        ldsB[c] = &Bls[chunk << 9];
    }

    // ---- hoisted LDS fragment byte-offsets (loop-invariant) ----
    const int r   = lane & 15;
    const int cb0 = lane >> 4;           // 0..3
    int aofs[2][4], bofs[2][4];
#pragma unroll
    for (int kk = 0; kk < 2; ++kk) {
        const int CB = (kk << 2) + cb0;  // col-block 0..7
#pragma unroll
        for (int i = 0; i < 4; ++i) {
            const int ar = wm + (i << 4) + r;
            aofs[kk][i] = ar * 128 + ((CB ^ (ar & 7)) << 4);   // bytes
            const int br = wn + (i << 4) + r;
            bofs[kk][i] = br * 128 + ((CB ^ (br & 7)) << 4);
        }
    }
    const char* AbB = (const char*)Als;
    const char* BbB = (const char*)Bls;

    for (int k0 = 0; k0 < Keff; k0 += 64) {
        __syncthreads();   // protect LDS from previous iteration's readers
#pragma unroll
        for (int c = 0; c < 4; ++c) {
            __builtin_amdgcn_global_load_lds(GLB_AS(gaP[c]), LDS_AS(ldsA[c]), 16, 0, 0);
            __builtin_amdgcn_global_load_lds(GLB_AS(gbP[c]), LDS_AS(ldsB[c]), 16, 0, 0);
            gaP[c] += 64;
            gbP[c] += 64;
        }
        __syncthreads();   // drain global_load_lds (vmcnt) + visibility

#pragma unroll
        for (int kk = 0; kk < 2; ++kk) {
            short8 afr[4], bfr[4];
#pragma unroll
            for (int i = 0; i < 4; ++i)
                afr[i] = *(const short8*)(AbB + aofs[kk][i]);
#pragma unroll
            for (int j = 0; j < 4; ++j)
                bfr[j] = *(const short8*)(BbB + bofs[kk][j]);
#pragma unroll
            for (int i = 0; i < 4; ++i)
#pragma unroll
                for (int j = 0; j < 4; ++j)
                    acc[i][j] = __builtin_amdgcn_mfma_f32_16x16x32_bf16(
                        afr[i], bfr[j], acc[i][j], 0, 0, 0);
        }
    }

    // epilogue: C/D layout col=lane&15, row=(lane>>4)*4+reg
    const int ccol = lane & 15;
    const int crow = (lane >> 4) << 2;
#pragma unroll
    for (int i = 0; i < 4; ++i) {
#pragma unroll
        for (int j = 0; j < 4; ++j) {
            const int col  = n0 + wn + (j << 4) + ccol;
            const int rowb = m0 + wm + (i << 4) + crow;
#pragma unroll
            for (int r2 = 0; r2 < 4; ++r2) {
                const int row = rowb + r2;
                float v = acc[i][j][r2];
                const long cidx = coff + (long)row * ldc + col;
                if (EPI == 3) {
                    int d0 = row - col;
                    int ad = d0 < 0 ? -d0 : d0;
                    if (ad > 250) ad = 250;
                    // causal masking handled in softmax; just add dist bias
                    ((bf16*)Cv)[cidx] = __float2bfloat16(v * scale + demb[ad * 8 + zi]);
                } else if (EPI == 0) {
                    if (bias) v += bias[col];
                    ((float*)Cv)[cidx] = v;
                } else if (EPI == 1 || EPI == 4) {
                    if (bias) v += bias[col];
                    ((bf16*)Cv)[cidx] = __float2bfloat16(v);
                } else {
                    v += bias[col];
                    v = 0.5f * v * (1.0f + erff(v * 0.70710678118f));
                    ((bf16*)Cv)[cidx] = __float2bfloat16(v);
                }
            }
        }
    }
}

// ---------------------------------------------------------------------------
// merged fp32 -> bf16 cast over 4 weight arrays (counts in 4-elem groups)
// ---------------------------------------------------------------------------
__global__ void cast4_kernel(const float* __restrict__ s0, const float* __restrict__ s1,
                             const float* __restrict__ s2, const float* __restrict__ s3,
                             bf16* __restrict__ d0, bf16* __restrict__ d1,
                             bf16* __restrict__ d2, bf16* __restrict__ d3,
                             long n0, long n1, long n2, long n3)
{
    long i = (long)blockIdx.x * blockDim.x + threadIdx.x;
    const float* s; bf16* d; long base;
    if (i < n0)                { s = s0; d = d0; base = 0; }
    else if (i < n0 + n1)      { s = s1; d = d1; base = n0; }
    else if (i < n0 + n1 + n2) { s = s2; d = d2; base = n0 + n1; }
    else if (i < n0+n1+n2+n3)  { s = s3; d = d3; base = n0 + n1 + n2; }
    else return;
    const long j = i - base;
    f32x4 v = *(const f32x4*)(s + j * 4);
    bf16 t[4] = {__float2bfloat16(v[0]), __float2bfloat16(v[1]),
                 __float2bfloat16(v[2]), __float2bfloat16(v[3])};
    *(short4*)(d + j * 4) = *(const short4*)t;
}

// ---------------------------------------------------------------------------
// embedding: x[t,:] = token_emb[seq[t]] * 32  (sqrt(1024)); writes f32 + bf16
// ---------------------------------------------------------------------------
__global__ void embed_kernel(const int* __restrict__ seq, const float* __restrict__ emb,
                             float* __restrict__ x, bf16* __restrict__ xb)
{
    const long t = blockIdx.x;
    const int tok = seq[t];
    const int tid = threadIdx.x;
    f32x4 v = *(const f32x4*)(emb + (long)tok * 1024 + tid * 4);
    v *= 32.0f;
    *(f32x4*)(x + t * 1024 + tid * 4) = v;
    bf16 tq[4] = {__float2bfloat16(v[0]), __float2bfloat16(v[1]),
                  __float2bfloat16(v[2]), __float2bfloat16(v[3])};
    *(short4*)(xb + t * 1024 + tid * 4) = *(const short4*)tq;
}

// ---------------------------------------------------------------------------
// Causal softmax over rows of 256 (scores bf16 -> probs bf16). 1 wave/row.
// ---------------------------------------------------------------------------
__global__ void softmax_kernel(const bf16* __restrict__ scores, bf16* __restrict__ probs)
{
    const long row = (long)blockIdx.x * 4 + (threadIdx.x >> 6);
    const int q = (int)(row & 255);
    const int lane = threadIdx.x & 63;
    const int kbase = lane * 4;
    short4 sv = *(const short4*)(scores + row * 256 + kbase);
    const bf16* sp = (const bf16*)&sv;
    float v0 = (kbase + 0 <= q) ? __bfloat162float(sp[0]) : -1e30f;
    float v1 = (kbase + 1 <= q) ? __bfloat162float(sp[1]) : -1e30f;
    float v2 = (kbase + 2 <= q) ? __bfloat162float(sp[2]) : -1e30f;
    float v3 = (kbase + 3 <= q) ? __bfloat162float(sp[3]) : -1e30f;
    float m = fmaxf(fmaxf(v0, v1), fmaxf(v2, v3));
#pragma unroll
    for (int off = 32; off; off >>= 1) m = fmaxf(m, __shfl_xor(m, off));
    float e0 = (kbase + 0 <= q) ? __expf(v0 - m) : 0.f;
    float e1 = (kbase + 1 <= q) ? __expf(v1 - m) : 0.f;
    float e2 = (kbase + 2 <= q) ? __expf(v2 - m) : 0.f;
    float e3 = (kbase + 3 <= q) ? __expf(v3 - m) : 0.f;
    float s = e0 + e1 + e2 + e3;
#pragma unroll
    for (int off = 32; off; off >>= 1) s += __shfl_xor(s, off);
    const float inv = 1.0f / s;
    bf16 tq[4] = {__float2bfloat16(e0 * inv), __float2bfloat16(e1 * inv),
                  __float2bfloat16(e2 * inv), __float2bfloat16(e3 * inv)};
    *(short4*)(probs + row * 256 + kbase) = *(const short4*)tq;
}

// ---------------------------------------------------------------------------
// V transpose: qkv[b,s,2E + h*128 + d] -> vt[b,h,d,s]  (bf16), LDS 32x33 tile
// ---------------------------------------------------------------------------
__global__ void transpose_v(const bf16* __restrict__ qkv, bf16* __restrict__ vt)
{
    __shared__ bf16 tile[32][33];
    const int bh = blockIdx.y;
    const int st = blockIdx.x & 7;
    const int dt = blockIdx.x >> 3;
    const int tx = threadIdx.x & 31;
    const int ty = threadIdx.x >> 5;   // 0..7
    const int b = bh >> 3, h = bh & 7;
    const bf16* src = qkv + ((long)b * 256) * 3072 + 2048 + h * 128 + dt * 32;
#pragma unroll
    for (int i = 0; i < 4; ++i) {
        const int s = st * 32 + ty * 4 + i;
        tile[ty * 4 + i][tx] = src[(long)s * 3072 + tx];
    }
    __syncthreads();
    bf16* dst = vt + ((long)bh * 128 + dt * 32) * 256 + st * 32;
#pragma unroll
    for (int i = 0; i < 4; ++i) {
        const int dl = ty * 4 + i;
        dst[(long)dl * 256 + tx] = tile[tx][dl];
    }
}

// ---------------------------------------------------------------------------
// LayerNorm over E=1024: out = (x [+ res(bf16)] - mean)/sqrt(var+1e-5)*g + b
// ---------------------------------------------------------------------------
__global__ void ln_kernel(const float* __restrict__ x, const bf16* __restrict__ res,
                          const float* __restrict__ g, const float* __restrict__ bta,
                          float* __restrict__ outf, bf16* __restrict__ outb,
                          int has_res, int has_bf)
{
    const long t = blockIdx.x;
    const int tid = threadIdx.x;
    f32x4 v = *(const f32x4*)(x + t * 1024 + tid * 4);
    if (has_res) {
        short4 rv = *(const short4*)(res + t * 1024 + tid * 4);
        const bf16* rp = (const bf16*)&rv;
#pragma unroll
        for (int q = 0; q < 4; ++q) v[q] += __bfloat162float(rp[q]);
    }
    float s  = v[0] + v[1] + v[2] + v[3];
    float ss = v[0]*v[0] + v[1]*v[1] + v[2]*v[2] + v[3]*v[3];
#pragma unroll
    for (int off = 32; off; off >>= 1) {
        s  += __shfl_xor(s, off);
        ss += __shfl_xor(ss, off);
    }
    __shared__ float red[8];
    const int w = tid >> 6;
    if ((tid & 63) == 0) { red[w] = s; red[4 + w] = ss; }
    __syncthreads();
    s  = red[0] + red[1] + red[2] + red[3];
    ss = red[4] + red[5] + red[6] + red[7];
    const float mean = s * (1.0f / 1024.0f);
    const float var  = ss * (1.0f / 1024.0f) - mean * mean;
    const float rstd = rsqrtf(var + 1e-5f);
    f32x4 gv = *(const f32x4*)(g + tid * 4);
    f32x4 bv = *(const f32x4*)(bta + tid * 4);
    f32x4 o;
#pragma unroll
    for (int q = 0; q < 4; ++q) o[q] = (v[q] - mean) * rstd * gv[q] + bv[q];
    *(f32x4*)(outf + t * 1024 + tid * 4) = o;
    if (has_bf) {
        bf16 tq[4] = {__float2bfloat16(o[0]), __float2bfloat16(o[1]),
                      __float2bfloat16(o[2]), __float2bfloat16(o[3])};
        *(short4*)(outb + t * 1024 + tid * 4) = *(const short4*)tq;
    }
}

// ---------------------------------------------------------------------------
// logits: out[t,n] = xf[t,:].dot(W[n,:]) + b[n], N=45, K=1024 (fp32)
// ---------------------------------------------------------------------------
__global__ void gen_kernel(const float* __restrict__ xf, const float* __restrict__ W,
                           const float* __restrict__ bias, float* __restrict__ out)
{
    const long t = (long)blockIdx.x * 4 + (threadIdx.x >> 6);
    const int lane = threadIdx.x & 63;
    const float* xr = xf + t * 1024;
    float xv[16];
#pragma unroll
    for (int j = 0; j < 16; ++j) xv[j] = xr[lane + 64 * j];
    for (int n = 0; n < 45; ++n) {
        const float* wr = W + (long)n * 1024;
        float a = 0.f;
#pragma unroll
        for (int j = 0; j < 16; ++j) a += xv[j] * wr[lane + 64 * j];
#pragma unroll
        for (int off = 32; off; off >>= 1) a += __shfl_xor(a, off);
        if (lane == 0) out[t * 45 + n] = a + bias[n];
    }
}

// ---------------------------------------------------------------------------
extern "C" void kernel_launch(void* const* d_in, const int* in_sizes, int n_in,
                              void* d_out, int out_size, void* d_ws, size_t ws_size,
                              hipStream_t stream)
{
    (void)in_sizes; (void)n_in; (void)out_size; (void)ws_size;
    const int*   seq  = (const int*)d_in[0];
    const float* temb = (const float*)d_in[1];
    const float* demb = (const float*)d_in[2];
    const float* Wqkv = (const float*)d_in[3];
    const float* bqkv = (const float*)d_in[4];
    const float* Wo   = (const float*)d_in[5];
    const float* bo   = (const float*)d_in[6];
    const float* W1   = (const float*)d_in[7];
    const float* b1   = (const float*)d_in[8];
    const float* W2   = (const float*)d_in[9];
    const float* b2   = (const float*)d_in[10];
    const float* ln1g = (const float*)d_in[11];
    const float* ln1b = (const float*)d_in[12];
    const float* ln2g = (const float*)d_in[13];
    const float* ln2b = (const float*)d_in[14];
    const float* fng  = (const float*)d_in[15];
    const float* fnb  = (const float*)d_in[16];
    const float* genW = (const float*)d_in[17];
    const float* genb = (const float*)d_in[18];
    float* out = (float*)d_out;

    char* ws = (char*)d_ws;
    size_t off = 0;
    auto alloc = [&](size_t bytes) -> char* {
        char* p = ws + off;
        off += (bytes + 255) & ~(size_t)255;
        return p;
    };

    // Lifetime-aliased workspace (~210 MB total):
    bf16*  wqkv_l = (bf16*)alloc(3072ULL * 1024 * 2);    //  6.3 MB
    bf16*  wo_l   = (bf16*)alloc(1024ULL * 1024 * 2);    //  2.1 MB
    bf16*  w1_l   = (bf16*)alloc(4096ULL * 1024 * 2);    //  8.4 MB
    bf16*  w2_l   = (bf16*)alloc(1024ULL * 4096 * 2);    //  8.4 MB
    float* x      = (float*)alloc(8192ULL * 1024 * 4);   // 33.6 MB
    bf16*  xb     = (bf16*)alloc(8192ULL * 1024 * 2);    // 16.8 MB
    char*  qkvreg = alloc(8192ULL * 3072 * 2);           // 50.3 MB
    char*  R      = alloc(8192ULL * 4096 * 2);           // 67.1 MB
    bf16*  tmpb   = (bf16*)alloc(8192ULL * 1024 * 2);    // 16.8 MB

    bf16*  qkvb   = (bf16*)qkvreg;                       // [B,S,3E] bf16
    bf16*  attnb  = (bf16*)qkvreg;                       // aliases qkv (dead at PV time)
    float* lnout  = (float*)qkvreg;                      // final-LN f32 (end only)
    bf16*  scoreb = (bf16*)R;                            // [B,H,S,S] bf16 (first half)
    bf16*  probs  = (bf16*)(R + 8192ULL * 4096);         // second half of R
    bf16*  vt     = (bf16*)R;                            // aliases scores (dead after softmax)
    bf16*  hbuf   = (bf16*)R;                            // FFN hidden, full R

    const dim3 blk(256);

    embed_kernel<<<8192, blk, 0, stream>>>(seq, temb, x, xb);

    for (int l = 0; l < 6; ++l) {
        cast4_kernel<<<12288, blk, 0, stream>>>(
            Wqkv + (long)l * 3072 * 1024, Wo + (long)l * 1024 * 1024,
            W1 + (long)l * 4096 * 1024,   W2 + (long)l * 4096 * 1024,
            wqkv_l, wo_l, w1_l, w2_l,
            786432, 262144, 1048576, 1048576);

        // QKV: [8192,1024] x [3072,1024]^T -> bf16 [8192,3072]
        gemm_bf16<1><<<dim3(64, 24, 1), blk, 0, stream>>>(xb, wqkv_l, qkvb,
            1024, 1024, 1024, 3072, 0, 0, 0, 0, 0, 0, 1,
            bqkv + (long)l * 3072, nullptr, 0.f);

        // scores[b,h,q,k] = scale*(Q.K) + dist bias (bf16); 3 causal tiles only
        gemm_bf16<3><<<dim3(3, 1, 256), blk, 0, stream>>>(qkvb, qkvb + 1024, scoreb,
            128, 3072, 3072, 256,
            786432, 128, 786432, 128, 524288, 65536, 8,
            nullptr, demb, 0.08838834764831845f);

        softmax_kernel<<<16384, blk, 0, stream>>>(scoreb, probs);
        transpose_v<<<dim3(32, 256), blk, 0, stream>>>(qkvb, vt);   // vt overwrites scores (dead)

        // O[b,q,h*128+d] = P.V ; causal K-limit per q-tile
        gemm_bf16<4><<<dim3(2, 1, 256), blk, 0, stream>>>(probs, vt, attnb,
            256, 256, 256, 1024,
            524288, 65536, 262144, 32768, 262144, 128, 8,
            nullptr, nullptr, 0.f);

        // Wo: [8192,1024] x [1024,1024]^T -> bf16 tmpb
        gemm_bf16<1><<<dim3(64, 8, 1), blk, 0, stream>>>(attnb, wo_l, tmpb,
            1024, 1024, 1024, 1024, 0, 0, 0, 0, 0, 0, 1,
            bo + (long)l * 1024, nullptr, 0.f);

        ln_kernel<<<8192, blk, 0, stream>>>(x, tmpb, ln1g + (long)l * 1024,
                                            ln1b + (long)l * 1024, x, xb, 1, 1);

        // FFN1 + GELU: [8192,1024] x [4096,1024]^T -> bf16 [8192,4096]
        gemm_bf16<2><<<dim3(64, 32, 1), blk, 0, stream>>>(xb, w1_l, hbuf,
            1024, 1024, 1024, 4096, 0, 0, 0, 0, 0, 0, 1,
            b1 + (long)l * 4096, nullptr, 0.f);

        // FFN2: [8192,4096] x [1024,4096]^T -> bf16 tmpb
        gemm_bf16<1><<<dim3(64, 8, 1), blk, 0, stream>>>(hbuf, w2_l, tmpb,
            4096, 4096, 4096, 1024, 0, 0, 0, 0, 0, 0, 1,
            b2 + (long)l * 1024, nullptr, 0.f);

        ln_kernel<<<8192, blk, 0, stream>>>(x, tmpb, ln2g + (long)l * 1024,
                                            ln2b + (long)l * 1024, x, xb, 1, 1);
    }

    // final LN (no residual) -> lnout (f32), then logits
    ln_kernel<<<8192, blk, 0, stream>>>(x, nullptr, fng, fnb, lnout, nullptr, 0, 0);
    gen_kernel<<<2048, blk, 0, stream>>>(lnout, genW, genb, out);
}